// Round 1
// baseline (1579.394 us; speedup 1.0000x reference)
//
#include <hip/hip_runtime.h>
#include <hip/hip_bf16.h>
#include <cstddef>

// Problem sizes (fixed by reference setup_inputs)
#define B_   8
#define CIN  96
#define H_   256
#define W_   256
#define CO1  48          // conv1 output channels
#define NCH  192         // final output channels (CO1*4)
#define HO   128
#define WO   128

// ---------------------------------------------------------------------------
// Kernel 0: transpose w_body[co][ci][3][3] -> wt[ci][co][3][3]
// so conv1's inner loop reads contiguous, wave-uniform weight vectors.
// ---------------------------------------------------------------------------
__global__ void transpose_wb(const float* __restrict__ wb, float* __restrict__ wt) {
    int i = blockIdx.x * blockDim.x + threadIdx.x;   // flat over 48*96*9
    if (i >= CO1 * CIN * 9) return;
    int k  = i % 9;
    int ci = (i / 9) % CIN;
    int co = i / (9 * CIN);
    wt[(ci * CO1 + co) * 9 + k] = wb[i];
}

// ---------------------------------------------------------------------------
// Kernel 1: y = conv3x3_same(x, w_body)   (fp32 direct conv)
// block = 256 threads = 4 rows x 64 cols pixel tile; 48 accumulators/thread.
// grid  = (W_/64, H_/4, B_)
// ---------------------------------------------------------------------------
__global__ __launch_bounds__(256) void conv1_kernel(
    const float* __restrict__ x, const float* __restrict__ wt,
    float* __restrict__ y)
{
    __shared__ float sx[6][72];   // 6 rows x 66 cols used (stride 72)

    const int tid = threadIdx.x;
    const int tx  = tid & 63;
    const int ty  = tid >> 6;
    const int w0  = blockIdx.x * 64;
    const int h0  = blockIdx.y * 4;
    const int b   = blockIdx.z;

    const float* xb = x + (size_t)b * CIN * H_ * W_;

    float acc[CO1];
#pragma unroll
    for (int i = 0; i < CO1; ++i) acc[i] = 0.f;

    for (int ci = 0; ci < CIN; ++ci) {
        const float* xc = xb + (size_t)ci * (H_ * W_);
        // stage 6x66 tile (rows h0-1..h0+4, cols w0-1..w0+64), zero-padded
        for (int i = tid; i < 6 * 66; i += 256) {
            int r = i / 66, cc = i % 66;
            int gh = h0 - 1 + r;
            int gw = w0 - 1 + cc;
            float v = 0.f;
            if ((unsigned)gh < (unsigned)H_ && (unsigned)gw < (unsigned)W_)
                v = xc[gh * W_ + gw];
            sx[r][cc] = v;
        }
        __syncthreads();

        float xv[9];
#pragma unroll
        for (int kh = 0; kh < 3; ++kh)
#pragma unroll
            for (int kw = 0; kw < 3; ++kw)
                xv[kh * 3 + kw] = sx[ty + kh][tx + kw];

        const float* wc = wt + ci * (CO1 * 9);   // uniform -> s_load
#pragma unroll
        for (int co = 0; co < CO1; ++co) {
#pragma unroll
            for (int k = 0; k < 9; ++k)
                acc[co] = fmaf(wc[co * 9 + k], xv[k], acc[co]);
        }
        __syncthreads();
    }

    const size_t base = ((size_t)b * CO1) * (H_ * W_) + (size_t)(h0 + ty) * W_ + (w0 + tx);
#pragma unroll
    for (int co = 0; co < CO1; ++co)
        y[base + (size_t)co * (H_ * W_)] = acc[co];
}

// ---------------------------------------------------------------------------
// Kernel 2: fused pixel-unshuffle + mask-gather + grouped conv3x3.
// out[b,n,H,W] = sum_{kh,kw} wp[n,0,kh,kw]*y[b,n/4, 2(H+kh-1)+dy, 2(W+kw-1)+dx]
//              + wp[n,1,kh,kw]*mask[b,0, 2(H+kh-1)+dy, 2(W+kw-1)+dx]
// with (dy,dx) = ((n%4)/2, n%2); zero-pad when H+kh-1 or W+kw-1 outside [0,128).
// grid = (1, HO/2, B_*NCH), block = (128, 2)  -> n uniform per block.
// ---------------------------------------------------------------------------
__global__ __launch_bounds__(256) void conv2_kernel(
    const float* __restrict__ y, const float* __restrict__ mask,
    const float* __restrict__ wproj, float* __restrict__ out)
{
    const int W  = threadIdx.x;                        // 0..127
    const int H  = blockIdx.y * 2 + threadIdx.y;       // 0..127
    const int bn = blockIdx.z;                         // b*192 + n
    const int b  = bn / NCH;
    const int n  = bn - b * NCH;
    const int c  = n >> 2;
    const int dy = (n >> 1) & 1;
    const int dx = n & 1;

    const float* wp = wproj + n * 18;                  // uniform -> s_load
    const float* yc = y    + ((size_t)b * CO1 + c) * (H_ * W_);
    const float* mb = mask + (size_t)b * (H_ * W_);

    float acc = 0.f;
#pragma unroll
    for (int kh = 0; kh < 3; ++kh) {
        const int hh = H + kh - 1;
        const bool rok = (unsigned)hh < (unsigned)HO;
        const int r = 2 * hh + dy;
#pragma unroll
        for (int kw = 0; kw < 3; ++kw) {
            const int ww = W + kw - 1;
            const bool ok = rok && ((unsigned)ww < (unsigned)WO);
            const int s = 2 * ww + dx;
            float yv = 0.f, mv = 0.f;
            if (ok) {
                yv = yc[r * W_ + s];
                mv = mb[r * W_ + s];
            }
            acc = fmaf(wp[kh * 3 + kw],     yv, acc);
            acc = fmaf(wp[9 + kh * 3 + kw], mv, acc);
        }
    }
    out[((size_t)bn * HO + H) * WO + W] = acc;
}

// ---------------------------------------------------------------------------
extern "C" void kernel_launch(void* const* d_in, const int* in_sizes, int n_in,
                              void* d_out, int out_size, void* d_ws, size_t ws_size,
                              hipStream_t stream) {
    const float* x      = (const float*)d_in[0];   // (8,96,256,256)
    const float* mask   = (const float*)d_in[1];   // (8,1,256,256)
    const float* w_body = (const float*)d_in[2];   // (48,96,3,3)
    const float* w_proj = (const float*)d_in[3];   // (192,2,3,3)
    float* out = (float*)d_out;                    // (8,192,128,128)

    // workspace layout: [wt: 48*96*9 floats][y: 8*48*256*256 floats]
    float* wt = (float*)d_ws;
    float* y  = (float*)((char*)d_ws + ((CO1 * CIN * 9 * sizeof(float) + 255) & ~255ull));

    // 0) weight transpose for conv1
    {
        int n = CO1 * CIN * 9;
        transpose_wb<<<(n + 255) / 256, 256, 0, stream>>>(w_body, wt);
    }
    // 1) main conv: x -> y
    {
        dim3 grid(W_ / 64, H_ / 4, B_);
        conv1_kernel<<<grid, 256, 0, stream>>>(x, wt, y);
    }
    // 2) fused unshuffle + grouped conv -> out
    {
        dim3 grid(1, HO / 2, B_ * NCH);
        dim3 block(128, 2, 1);
        conv2_kernel<<<grid, block, 0, stream>>>(y, mask, w_proj, out);
    }
}

// Round 2
// 565.858 us; speedup vs baseline: 2.7911x; 2.7911x over previous
//
#include <hip/hip_runtime.h>
#include <hip/hip_bf16.h>
#include <cstddef>

#define B_   8
#define CIN  96
#define H_   256
#define W_   256
#define CO1  48          // conv1 output channels
#define NCH  192         // final output channels (CO1*4)
#define HO   128
#define WO   128
#define HP   258         // padded NHWC height/width (1-px zero halo)

typedef short  v8s __attribute__((ext_vector_type(8)));   // 8 x bf16 (4 VGPRs)
typedef float  v4f __attribute__((ext_vector_type(4)));   // MFMA acc frag

static __device__ __forceinline__ unsigned short f2bf(float f) {
    __hip_bfloat16 h = __float2bfloat16(f);   // RNE
    return *(unsigned short*)&h;
}

// ---------------------------------------------------------------------------
// Prep A: w_body[co][ci][kh][kw] fp32 -> wbf[tap][co][ci] bf16
// (A-operand layout: lane = co, 8 contiguous ci per lane-quad)
// ---------------------------------------------------------------------------
__global__ void prep_weights(const float* __restrict__ wb, unsigned short* __restrict__ wbf) {
    int o = blockIdx.x * blockDim.x + threadIdx.x;      // flat over 9*48*96
    if (o >= 9 * CO1 * CIN) return;
    int ci  = o % CIN;
    int co  = (o / CIN) % CO1;
    int tap = o / (CIN * CO1);
    wbf[o] = f2bf(wb[(co * CIN + ci) * 9 + tap]);
}

// ---------------------------------------------------------------------------
// Prep B: mask (8,1,256,256) -> m_us (8,4,128,128)  (pixel-unshuffle, fp32)
// ---------------------------------------------------------------------------
__global__ void prep_mask(const float* __restrict__ mask, float* __restrict__ m_us) {
    int o = blockIdx.x * blockDim.x + threadIdx.x;      // flat over 8*4*128*128
    if (o >= B_ * 4 * HO * WO) return;
    int w1 = o & (WO - 1);
    int h1 = (o >> 7) & (HO - 1);
    int q  = (o >> 14) & 3;                             // 2*dy + dx
    int b  = o >> 16;
    int dy = q >> 1, dx = q & 1;
    m_us[o] = mask[((size_t)b * H_ + (2 * h1 + dy)) * W_ + (2 * w1 + dx)];
}

// ---------------------------------------------------------------------------
// Prep C: zero the 1-px halo border of xt (ws is poisoned 0xAA each launch)
// ---------------------------------------------------------------------------
__global__ void zero_border(unsigned short* __restrict__ xt) {
    int o = blockIdx.x * blockDim.x + threadIdx.x;      // flat over 8*1028*96
    const int NPIX = 2 * HP + 2 * (HP - 2);             // 1028 border pixels
    if (o >= B_ * NPIX * CIN) return;
    int ci = o % CIN;
    int p  = (o / CIN) % NPIX;
    int b  = o / (CIN * NPIX);
    int r, c;
    if      (p < HP)          { r = 0;            c = p; }
    else if (p < 2 * HP)      { r = HP - 1;       c = p - HP; }
    else if (p < 2 * HP + 256){ r = p - 2*HP + 1; c = 0; }
    else                      { r = p - (2*HP + 256) + 1; c = HP - 1; }
    xt[(((size_t)b * HP + r) * HP + c) * CIN + ci] = 0;
}

// ---------------------------------------------------------------------------
// Prep D: x (8,96,256,256) fp32 NCHW -> xt bf16 NHWC (8,258,258,96), interior.
// One thread per pixel: 96 coalesced dword loads, 12 dwordx4 stores.
// ---------------------------------------------------------------------------
__global__ __launch_bounds__(256) void transpose_x(const float* __restrict__ x,
                                                   unsigned short* __restrict__ xt) {
    int t = blockIdx.x * blockDim.x + threadIdx.x;      // flat over 8*65536
    int pix = t & (H_ * W_ - 1);
    int b   = t >> 16;
    int h   = pix >> 8, w = pix & 255;

    unsigned int vals[CIN / 2];
#pragma unroll
    for (int ci = 0; ci < CIN; ci += 2) {
        float f0 = x[(((size_t)b * CIN + ci)     << 16) + pix];
        float f1 = x[(((size_t)b * CIN + ci + 1) << 16) + pix];
        vals[ci >> 1] = (unsigned int)f2bf(f0) | ((unsigned int)f2bf(f1) << 16);
    }
    unsigned short* dst = xt + (((size_t)b * HP + (h + 1)) * HP + (w + 1)) * CIN;
#pragma unroll
    for (int j = 0; j < 12; ++j)
        ((int4*)dst)[j] = ((const int4*)vals)[j];
}

// ---------------------------------------------------------------------------
// conv1: implicit GEMM via MFMA. A = weights (M=48 co), B = pixels (N),
// K = 9 taps x 96 ci. Block = 4 waves, each wave = 64 consecutive W pixels
// of one row. No LDS, no barriers. Output written pixel-unshuffled:
// y_us[b][n=4c+2dy+dx][h'][w'] fp32 NCHW (192 ch, 128x128).
// ---------------------------------------------------------------------------
__global__ __launch_bounds__(256) void conv1_mfma(const unsigned short* __restrict__ xt,
                                                  const unsigned short* __restrict__ wbf,
                                                  float* __restrict__ y_us) {
    const int tid  = threadIdx.x;
    const int lane = tid & 63;
    const int wv   = tid >> 6;
    const int h    = blockIdx.x;          // output row 0..255
    const int b    = blockIdx.y;
    const int w0   = wv * 64;
    const int l15  = lane & 15;
    const int l4   = lane >> 4;

    // per-lane base addresses (element units)
    const unsigned short* aln = wbf + (l15 * CIN + l4 * 8);
    const unsigned short* bln = xt + (((size_t)b * HP + h) * HP + w0) * CIN
                                   + ((size_t)l15 * CIN + l4 * 8);

    v4f acc[12];
#pragma unroll
    for (int i = 0; i < 12; ++i) acc[i] = (v4f){0.f, 0.f, 0.f, 0.f};

    for (int tap = 0; tap < 9; ++tap) {
        const int kh = tap / 3, kw = tap % 3;
        const unsigned short* bt = bln + ((size_t)kh * HP + kw) * CIN;
        const unsigned short* at = aln + (size_t)tap * CO1 * CIN;
#pragma unroll
        for (int ks = 0; ks < 3; ++ks) {
            v8s a0 = *(const v8s*)(at +  0 * CIN + ks * 32);
            v8s a1 = *(const v8s*)(at + 16 * CIN + ks * 32);
            v8s a2 = *(const v8s*)(at + 32 * CIN + ks * 32);
            v8s b0 = *(const v8s*)(bt +  0 * CIN + ks * 32);
            v8s b1 = *(const v8s*)(bt + 16 * CIN + ks * 32);
            v8s b2 = *(const v8s*)(bt + 32 * CIN + ks * 32);
            v8s b3 = *(const v8s*)(bt + 48 * CIN + ks * 32);
            acc[0]  = __builtin_amdgcn_mfma_f32_16x16x32_bf16(a0, b0, acc[0],  0, 0, 0);
            acc[1]  = __builtin_amdgcn_mfma_f32_16x16x32_bf16(a0, b1, acc[1],  0, 0, 0);
            acc[2]  = __builtin_amdgcn_mfma_f32_16x16x32_bf16(a0, b2, acc[2],  0, 0, 0);
            acc[3]  = __builtin_amdgcn_mfma_f32_16x16x32_bf16(a0, b3, acc[3],  0, 0, 0);
            acc[4]  = __builtin_amdgcn_mfma_f32_16x16x32_bf16(a1, b0, acc[4],  0, 0, 0);
            acc[5]  = __builtin_amdgcn_mfma_f32_16x16x32_bf16(a1, b1, acc[5],  0, 0, 0);
            acc[6]  = __builtin_amdgcn_mfma_f32_16x16x32_bf16(a1, b2, acc[6],  0, 0, 0);
            acc[7]  = __builtin_amdgcn_mfma_f32_16x16x32_bf16(a1, b3, acc[7],  0, 0, 0);
            acc[8]  = __builtin_amdgcn_mfma_f32_16x16x32_bf16(a2, b0, acc[8],  0, 0, 0);
            acc[9]  = __builtin_amdgcn_mfma_f32_16x16x32_bf16(a2, b1, acc[9],  0, 0, 0);
            acc[10] = __builtin_amdgcn_mfma_f32_16x16x32_bf16(a2, b2, acc[10], 0, 0, 0);
            acc[11] = __builtin_amdgcn_mfma_f32_16x16x32_bf16(a2, b3, acc[11], 0, 0, 0);
        }
    }

    // Epilogue: D row = co = mf*16 + l4*4 + r ; D col = pixel = w0 + nf*16 + l15
    const int dy = h & 1, hp1 = h >> 1;
#pragma unroll
    for (int mf = 0; mf < 3; ++mf) {
#pragma unroll
        for (int nf = 0; nf < 4; ++nf) {
            const int Wp = w0 + nf * 16 + l15;
            const int dx = Wp & 1, wp1 = Wp >> 1;
#pragma unroll
            for (int r = 0; r < 4; ++r) {
                const int co = mf * 16 + l4 * 4 + r;
                const int n  = co * 4 + dy * 2 + dx;
                y_us[(((size_t)b * NCH + n) << 14) + (hp1 << 7) + wp1] = acc[mf * 4 + nf][r];
            }
        }
    }
}

// ---------------------------------------------------------------------------
// conv2: plain unit-stride grouped 3x3 over (y_us[n], m_us[n&3]).
// grid = (1, HO/2, B_*NCH), block = (128, 2); n uniform per block -> s_load w.
// ---------------------------------------------------------------------------
__global__ __launch_bounds__(256) void conv2_kernel(
    const float* __restrict__ y_us, const float* __restrict__ m_us,
    const float* __restrict__ wproj, float* __restrict__ out)
{
    const int W  = threadIdx.x;
    const int H  = blockIdx.y * 2 + threadIdx.y;
    const int bn = blockIdx.z;                         // b*192 + n
    const int b  = bn / NCH;
    const int n  = bn - b * NCH;

    const float* wp = wproj + n * 18;                  // uniform -> s_load
    const float* yc = y_us + ((size_t)bn << 14);
    const float* mc = m_us + (((size_t)b * 4 + (n & 3)) << 14);

    float acc = 0.f;
#pragma unroll
    for (int kh = 0; kh < 3; ++kh) {
        const int hh = H + kh - 1;
        const bool rok = (unsigned)hh < (unsigned)HO;
#pragma unroll
        for (int kw = 0; kw < 3; ++kw) {
            const int ww = W + kw - 1;
            const bool ok = rok && ((unsigned)ww < (unsigned)WO);
            float yv = 0.f, mv = 0.f;
            if (ok) {
                yv = yc[hh * WO + ww];
                mv = mc[hh * WO + ww];
            }
            acc = fmaf(wp[kh * 3 + kw],     yv, acc);
            acc = fmaf(wp[9 + kh * 3 + kw], mv, acc);
        }
    }
    out[((size_t)bn << 14) + H * WO + W] = acc;
}

// ---------------------------------------------------------------------------
extern "C" void kernel_launch(void* const* d_in, const int* in_sizes, int n_in,
                              void* d_out, int out_size, void* d_ws, size_t ws_size,
                              hipStream_t stream) {
    const float* x      = (const float*)d_in[0];   // (8,96,256,256)
    const float* mask   = (const float*)d_in[1];   // (8,1,256,256)
    const float* w_body = (const float*)d_in[2];   // (48,96,3,3)
    const float* w_proj = (const float*)d_in[3];   // (192,2,3,3)
    float* out = (float*)d_out;                    // (8,192,128,128)

    // workspace layout
    char* p = (char*)d_ws;
    unsigned short* wbf = (unsigned short*)p;                 p += (9*CO1*CIN*2 + 255) & ~255ull;     // 83 KB
    float*          m_us = (float*)p;                         p += ((size_t)B_*4*HO*WO*4 + 255) & ~255ull; // 2 MB
    unsigned short* xt  = (unsigned short*)p;                 p += ((size_t)B_*HP*HP*CIN*2 + 255) & ~255ull; // 97.5 MB
    float*          y_us = (float*)p;                         // 100.7 MB

    {   int nel = 9 * CO1 * CIN;
        prep_weights<<<(nel + 255) / 256, 256, 0, stream>>>(w_body, wbf); }
    {   int nel = B_ * 4 * HO * WO;
        prep_mask<<<(nel + 255) / 256, 256, 0, stream>>>(mask, m_us); }
    {   int nel = B_ * (2 * HP + 2 * (HP - 2)) * CIN;
        zero_border<<<(nel + 255) / 256, 256, 0, stream>>>(xt); }
    {   int nel = B_ * H_ * W_;
        transpose_x<<<nel / 256, 256, 0, stream>>>(x, xt); }
    {   dim3 grid(H_, B_);
        conv1_mfma<<<grid, 256, 0, stream>>>(xt, wbf, y_us); }
    {   dim3 grid(1, HO / 2, B_ * NCH);
        dim3 block(WO, 2, 1);
        conv2_kernel<<<grid, block, 0, stream>>>(y_us, m_us, w_proj, out); }
}